// Round 1
// baseline (561.457 us; speedup 1.0000x reference)
//
#include <hip/hip_runtime.h>
#include <hip/hip_bf16.h>
#include <cstdint>

// Exphormer attention, MI355X.
// Pipeline: K1 convert weights (fp32 -> bf16 hi/lo split) ->
//           K2 QKV projection (bf16 MFMA, weight-split for accuracy) ->
//           K3 edge kernel: E projection + score = exp(clamp(sum(K[src]*Q[dst]*scale*E))) ->
//           K4 CSR build (hist, scan x3, scatter) ->
//           K5 gather: out[dst] = sum score * V[src]

typedef float  f32x4  __attribute__((ext_vector_type(4)));
typedef short  bf16x8 __attribute__((ext_vector_type(8)));

#define AP 136   // a_lds row stride (bf16 elems): 64x136x2 = 17408 B
#define EP 132   // e_lds row stride (f32 elems):  64x132x4 = 33792 B

__device__ __forceinline__ short f2bf(float f) {
    union { float f; uint32_t u; } v; v.f = f;
    uint32_t r = v.u + 0x7FFFu + ((v.u >> 16) & 1u);   // round-to-nearest-even
    return (short)(r >> 16);
}
__device__ __forceinline__ float bf2f(short s) {
    union { uint32_t u; float f; } v; v.u = ((uint32_t)(uint16_t)s) << 16;
    return v.f;
}

// ---------------- K1: weight conversion ----------------
// Wall row layout: [0:128)=Wq, [128:256)=Wk, [256:384)=Wv, [384:512)=We (bias same order)
__global__ __launch_bounds__(256) void convert_weights(
        const float* __restrict__ Wq, const float* __restrict__ bq,
        const float* __restrict__ Wk, const float* __restrict__ bk,
        const float* __restrict__ We, const float* __restrict__ be,
        const float* __restrict__ Wv, const float* __restrict__ bv,
        short* __restrict__ Whi, short* __restrict__ Wlo, float* __restrict__ ball) {
    int idx = blockIdx.x * 256 + threadIdx.x;     // 0..65535 exact
    int wrow = idx >> 7;                          // 0..511
    int k = idx & 127;
    int which = wrow >> 7;                        // 0 Q, 1 K, 2 V, 3 E
    int r = wrow & 127;
    const float* Wsrc = which == 0 ? Wq : which == 1 ? Wk : which == 2 ? Wv : We;
    float f = Wsrc[r * 128 + k];
    short hi = f2bf(f);
    short lo = f2bf(f - bf2f(hi));
    Whi[idx] = hi; Wlo[idx] = lo;
    if (idx < 512) {
        int wh = idx >> 7; int rr = idx & 127;
        const float* bsrc = wh == 0 ? bq : wh == 1 ? bk : wh == 2 ? bv : be;
        ball[idx] = bsrc[rr];
    }
}

// ---------------- shared MFMA core (64 rows x 128 cols, K=128) ----------------
// block = 256 threads = 4 waves; wave w owns cols [w*32, w*32+32) of the tile.
// A staged fp32->bf16 in LDS [64][AP]; B (weights hi+lo) read per-wave from global.

// ---------------- K2: QKV projection ----------------
__global__ __launch_bounds__(256) void qkv_kernel(
        const float* __restrict__ x,
        const short* __restrict__ Whi, const short* __restrict__ Wlo,
        const float* __restrict__ ball,
        float* __restrict__ Qb, float* __restrict__ Kb, float* __restrict__ Vb,
        int N) {
    __shared__ char lds[64 * EP * 4];
    const int t = threadIdx.x;
    const int m0 = blockIdx.x * 64;
    const int ct = blockIdx.y;                    // 0=Q, 1=K, 2=V

    // stage x tile -> bf16 LDS
#pragma unroll
    for (int i = 0; i < 4; ++i) {
        int g = t + i * 256;                      // 8-float group id, 0..1023
        int row = g >> 4, c8 = g & 15;
        int grow = m0 + row;
        float4 f0 = {0.f,0.f,0.f,0.f}, f1 = {0.f,0.f,0.f,0.f};
        if (grow < N) {
            const float4* p = (const float4*)(x + (size_t)grow * 128 + c8 * 8);
            f0 = p[0]; f1 = p[1];
        }
        union { short s[8]; int4 v; } u;
        u.s[0]=f2bf(f0.x); u.s[1]=f2bf(f0.y); u.s[2]=f2bf(f0.z); u.s[3]=f2bf(f0.w);
        u.s[4]=f2bf(f1.x); u.s[5]=f2bf(f1.y); u.s[6]=f2bf(f1.z); u.s[7]=f2bf(f1.w);
        *(int4*)(lds + row * (AP * 2) + c8 * 16) = u.v;
    }
    __syncthreads();

    const int w = t >> 6, lane = t & 63;
    const int r16 = lane & 15, g16 = lane >> 4;
    const int cb = w * 32;
    const int colbase = ct * 128;

    bf16x8 bh[2][4], bl[2][4];
#pragma unroll
    for (int n = 0; n < 2; ++n) {
        int colg = colbase + cb + n * 16 + r16;
#pragma unroll
        for (int ks = 0; ks < 4; ++ks) {
            bh[n][ks] = *(const bf16x8*)(Whi + colg * 128 + ks * 32 + g16 * 8);
            bl[n][ks] = *(const bf16x8*)(Wlo + colg * 128 + ks * 32 + g16 * 8);
        }
    }
    f32x4 acc[4][2];
#pragma unroll
    for (int m = 0; m < 4; ++m)
#pragma unroll
        for (int n = 0; n < 2; ++n) acc[m][n] = (f32x4){0.f,0.f,0.f,0.f};

#pragma unroll
    for (int ks = 0; ks < 4; ++ks) {
        bf16x8 a[4];
#pragma unroll
        for (int m = 0; m < 4; ++m)
            a[m] = *(const bf16x8*)(lds + (m * 16 + r16) * (AP * 2) + ks * 64 + g16 * 16);
#pragma unroll
        for (int m = 0; m < 4; ++m)
#pragma unroll
            for (int n = 0; n < 2; ++n) {
                acc[m][n] = __builtin_amdgcn_mfma_f32_16x16x32_bf16(a[m], bh[n][ks], acc[m][n], 0, 0, 0);
                acc[m][n] = __builtin_amdgcn_mfma_f32_16x16x32_bf16(a[m], bl[n][ks], acc[m][n], 0, 0, 0);
            }
    }
    float bias[2];
#pragma unroll
    for (int n = 0; n < 2; ++n) bias[n] = ball[colbase + cb + n * 16 + r16];

    __syncthreads();                              // done reading A; reuse LDS as E tile
    float* e_lds = (float*)lds;
#pragma unroll
    for (int m = 0; m < 4; ++m)
#pragma unroll
        for (int n = 0; n < 2; ++n)
#pragma unroll
            for (int r = 0; r < 4; ++r) {
                int row = m * 16 + g16 * 4 + r;
                int col = cb + n * 16 + r16;
                e_lds[row * EP + col] = acc[m][n][r] + bias[n];
            }
    __syncthreads();

    float* outb = ct == 0 ? Qb : ct == 1 ? Kb : Vb;
#pragma unroll
    for (int i = 0; i < 8; ++i) {
        int g = t + i * 256;                      // float4 unit, 0..2047
        int row = g >> 5, c4 = g & 31;
        int grow = m0 + row;
        if (grow < N) {
            float4 v = *(float4*)(lds + row * (EP * 4) + c4 * 16);
            *(float4*)(outb + (size_t)grow * 128 + c4 * 4) = v;
        }
    }
}

// ---------------- K3: edge kernel (E proj + score) ----------------
__global__ __launch_bounds__(256) void edge_kernel(
        const float* __restrict__ ea,
        const int* __restrict__ srcp, const int* __restrict__ dstp,
        const short* __restrict__ Whi, const short* __restrict__ Wlo,
        const float* __restrict__ ball,
        const float* __restrict__ Qb, const float* __restrict__ Kb,
        float* __restrict__ scores, int NE) {
    __shared__ char lds[64 * EP * 4];
    const int t = threadIdx.x;
    const int e0 = blockIdx.x * 64;

#pragma unroll
    for (int i = 0; i < 4; ++i) {
        int g = t + i * 256;
        int row = g >> 4, c8 = g & 15;
        int grow = e0 + row;
        float4 f0 = {0.f,0.f,0.f,0.f}, f1 = {0.f,0.f,0.f,0.f};
        if (grow < NE) {
            const float4* p = (const float4*)(ea + (size_t)grow * 128 + c8 * 8);
            f0 = p[0]; f1 = p[1];
        }
        union { short s[8]; int4 v; } u;
        u.s[0]=f2bf(f0.x); u.s[1]=f2bf(f0.y); u.s[2]=f2bf(f0.z); u.s[3]=f2bf(f0.w);
        u.s[4]=f2bf(f1.x); u.s[5]=f2bf(f1.y); u.s[6]=f2bf(f1.z); u.s[7]=f2bf(f1.w);
        *(int4*)(lds + row * (AP * 2) + c8 * 16) = u.v;
    }
    __syncthreads();

    const int w = t >> 6, lane = t & 63;
    const int r16 = lane & 15, g16 = lane >> 4;
    const int cb = w * 32;
    const int colbase = 384;                      // We rows in Wall

    bf16x8 bh[2][4], bl[2][4];
#pragma unroll
    for (int n = 0; n < 2; ++n) {
        int colg = colbase + cb + n * 16 + r16;
#pragma unroll
        for (int ks = 0; ks < 4; ++ks) {
            bh[n][ks] = *(const bf16x8*)(Whi + colg * 128 + ks * 32 + g16 * 8);
            bl[n][ks] = *(const bf16x8*)(Wlo + colg * 128 + ks * 32 + g16 * 8);
        }
    }
    f32x4 acc[4][2];
#pragma unroll
    for (int m = 0; m < 4; ++m)
#pragma unroll
        for (int n = 0; n < 2; ++n) acc[m][n] = (f32x4){0.f,0.f,0.f,0.f};

#pragma unroll
    for (int ks = 0; ks < 4; ++ks) {
        bf16x8 a[4];
#pragma unroll
        for (int m = 0; m < 4; ++m)
            a[m] = *(const bf16x8*)(lds + (m * 16 + r16) * (AP * 2) + ks * 64 + g16 * 16);
#pragma unroll
        for (int m = 0; m < 4; ++m)
#pragma unroll
            for (int n = 0; n < 2; ++n) {
                acc[m][n] = __builtin_amdgcn_mfma_f32_16x16x32_bf16(a[m], bh[n][ks], acc[m][n], 0, 0, 0);
                acc[m][n] = __builtin_amdgcn_mfma_f32_16x16x32_bf16(a[m], bl[n][ks], acc[m][n], 0, 0, 0);
            }
    }
    float bias[2];
#pragma unroll
    for (int n = 0; n < 2; ++n) bias[n] = ball[colbase + cb + n * 16 + r16];

    __syncthreads();
    float* e_lds = (float*)lds;
#pragma unroll
    for (int m = 0; m < 4; ++m)
#pragma unroll
        for (int n = 0; n < 2; ++n)
#pragma unroll
            for (int r = 0; r < 4; ++r) {
                int row = m * 16 + g16 * 4 + r;
                int col = cb + n * 16 + r16;
                e_lds[row * EP + col] = acc[m][n][r] + bias[n];
            }
    __syncthreads();

    // epilogue: per (edge, head) dot with K[src]*Q[dst]*scale, clamp, exp
#pragma unroll
    for (int it = 0; it < 2; ++it) {
        int task = t + it * 256;                  // 0..511
        int el = task >> 3, h = task & 7;
        int eg = e0 + el;
        if (eg < NE) {
            int s = srcp[eg], d = dstp[eg];
            const float4* Kp = (const float4*)(Kb + (size_t)s * 128 + h * 16);
            const float4* Qp = (const float4*)(Qb + (size_t)d * 128 + h * 16);
            float dot = 0.f;
#pragma unroll
            for (int j = 0; j < 4; ++j) {
                float4 ev = *(const float4*)(lds + el * (EP * 4) + h * 64 + j * 16);
                float4 kv = Kp[j];
                float4 qv = Qp[j];
                dot += ev.x * kv.x * qv.x + ev.y * kv.y * qv.y
                     + ev.z * kv.z * qv.z + ev.w * kv.w * qv.w;
            }
            float sv = fminf(fmaxf(dot * 0.25f, -5.0f), 5.0f);
            scores[(size_t)eg * 8 + h] = expf(sv);
        }
    }
}

// ---------------- K4: CSR build ----------------
__global__ __launch_bounds__(256) void hist_kernel(const int* __restrict__ dstp,
                                                   int* __restrict__ counts, int NE) {
    int i = blockIdx.x * 256 + threadIdx.x;
    if (i < NE) atomicAdd(&counts[dstp[i]], 1);
}

__global__ __launch_bounds__(1024) void scan1_kernel(const int* __restrict__ counts,
                                                     int* __restrict__ incl,
                                                     int* __restrict__ partials, int n) {
    __shared__ int sh[1024];
    int t = threadIdx.x;
    int i = blockIdx.x * 1024 + t;
    sh[t] = (i < n) ? counts[i] : 0;
    for (int off = 1; off < 1024; off <<= 1) {
        __syncthreads();
        int xv = (t >= off) ? sh[t - off] : 0;
        __syncthreads();
        sh[t] += xv;
    }
    __syncthreads();
    if (i < n) incl[i] = sh[t];
    if (t == 1023) partials[blockIdx.x] = sh[1023];
}

__global__ __launch_bounds__(64) void scan2_kernel(int* __restrict__ partials, int nb) {
    __shared__ int sh[64];
    int t = threadIdx.x;
    sh[t] = (t < nb) ? partials[t] : 0;
    __syncthreads();
    if (t == 0) {
        int acc = 0;
        for (int b = 0; b < nb; ++b) { int v = sh[b]; sh[b] = acc; acc += v; }
    }
    __syncthreads();
    if (t < nb) partials[t] = sh[t];
}

__global__ __launch_bounds__(1024) void scan3_kernel(const int* __restrict__ counts,
                                                     int* __restrict__ offsets,
                                                     int* __restrict__ cursors,
                                                     const int* __restrict__ partials,
                                                     int n, int total) {
    int i = blockIdx.x * 1024 + threadIdx.x;
    if (i < n) {
        int off = offsets[i] - counts[i] + partials[blockIdx.x];
        offsets[i] = off;
        cursors[i] = off;
    } else if (i == n) {
        offsets[n] = total;
    }
}

__global__ __launch_bounds__(256) void scatter_kernel(const int* __restrict__ dstp,
                                                      int* __restrict__ cursors,
                                                      int* __restrict__ ebuf, int NE) {
    int i = blockIdx.x * 256 + threadIdx.x;
    if (i < NE) {
        int d = dstp[i];
        int pos = atomicAdd(&cursors[d], 1);
        ebuf[pos] = i;
    }
}

// ---------------- K5: gather/aggregate ----------------
__global__ __launch_bounds__(256) void gather_kernel(
        const int* __restrict__ offsets, const int* __restrict__ ebuf,
        const int* __restrict__ srcp, const float* __restrict__ scores,
        const float* __restrict__ Vb, float* __restrict__ out, int N) {
    int node = blockIdx.x * 2 + (threadIdx.x >> 7);
    int col = threadIdx.x & 127;
    if (node >= N) return;
    int h = col >> 4;
    int beg = offsets[node], end = offsets[node + 1];
    float acc = 0.f;
    for (int j = beg; j < end; ++j) {
        int eid = ebuf[j];
        int s = srcp[eid];
        float sc = scores[(size_t)eid * 8 + h];
        acc += sc * Vb[(size_t)s * 128 + col];
    }
    out[(size_t)node * 128 + col] = acc;
}

// ---------------- launcher ----------------
extern "C" void kernel_launch(void* const* d_in, const int* in_sizes, int n_in,
                              void* d_out, int out_size, void* d_ws, size_t ws_size,
                              hipStream_t stream) {
    const float* x   = (const float*)d_in[0];
    const float* ea  = (const float*)d_in[1];
    const int* eidx  = (const int*)d_in[2];
    const float* Wq  = (const float*)d_in[4];  const float* bq = (const float*)d_in[5];
    const float* Wk  = (const float*)d_in[6];  const float* bk = (const float*)d_in[7];
    const float* We  = (const float*)d_in[8];  const float* be = (const float*)d_in[9];
    const float* Wv  = (const float*)d_in[10]; const float* bv = (const float*)d_in[11];
    const int N  = in_sizes[0] / 128;
    const int NE = in_sizes[2] / 2;
    const int* srcp = eidx;
    const int* dstp = eidx + NE;
    float* out = (float*)d_out;

    char* ws = (char*)d_ws;
    size_t o = 0;
    auto alloc = [&](size_t b) { size_t r = o; o += (b + 255) & ~(size_t)255; return r; };
    float* Qb      = (float*)(ws + alloc((size_t)N * 128 * 4));
    float* Kb      = (float*)(ws + alloc((size_t)N * 128 * 4));
    float* Vb      = (float*)(ws + alloc((size_t)N * 128 * 4));
    float* scores  = (float*)(ws + alloc((size_t)NE * 8 * 4));
    short* Whi     = (short*)(ws + alloc(512 * 128 * 2));
    short* Wlo     = (short*)(ws + alloc(512 * 128 * 2));
    float* ball    = (float*)(ws + alloc(512 * 4));
    int* counts    = (int*)(ws + alloc((size_t)(N + 1) * 4));
    int* offsets   = (int*)(ws + alloc((size_t)(N + 1) * 4));
    int* cursors   = (int*)(ws + alloc((size_t)N * 4));
    int* ebuf      = (int*)(ws + alloc((size_t)NE * 4));
    int* partials  = (int*)(ws + alloc(64 * 4));
    (void)ws_size; (void)n_in; (void)out_size;

    hipMemsetAsync(counts, 0, (size_t)(N + 1) * 4, stream);

    convert_weights<<<256, 256, 0, stream>>>(Wq, bq, Wk, bk, We, be, Wv, bv, Whi, Wlo, ball);

    dim3 gq((N + 63) / 64, 3);
    qkv_kernel<<<gq, 256, 0, stream>>>(x, Whi, Wlo, ball, Qb, Kb, Vb, N);

    edge_kernel<<<(NE + 63) / 64, 256, 0, stream>>>(ea, srcp, dstp, Whi, Wlo, ball,
                                                    Qb, Kb, scores, NE);

    hist_kernel<<<(NE + 255) / 256, 256, 0, stream>>>(dstp, counts, NE);
    int nb = (N + 1023) / 1024;
    scan1_kernel<<<nb, 1024, 0, stream>>>(counts, offsets, partials, N);
    scan2_kernel<<<1, 64, 0, stream>>>(partials, nb);
    scan3_kernel<<<nb, 1024, 0, stream>>>(counts, offsets, cursors, partials, N, NE);
    scatter_kernel<<<(NE + 255) / 256, 256, 0, stream>>>(dstp, cursors, ebuf, NE);

    gather_kernel<<<(N + 1) / 2, 256, 0, stream>>>(offsets, ebuf, srcp, scores, Vb, out, N);
}

// Round 3
// 405.354 us; speedup vs baseline: 1.3851x; 1.3851x over previous
//
#include <hip/hip_runtime.h>
#include <hip/hip_bf16.h>
#include <cstdint>

// Exphormer attention, MI355X.
// Pipeline: K1 convert weights (fp32 -> bf16 hi/lo split) ->
//           K2 fused QKV projection (bf16 MFMA, weight-split for accuracy) ->
//           K3 edge kernel: E projection + score + dst histogram ->
//           K4 CSR build (scan x3, scatter int2{srcoff,scoreoff}) ->
//           K5 gather: out[dst] = sum score * V[src]  (4-way unrolled)

typedef float  f32x4  __attribute__((ext_vector_type(4)));
typedef short  bf16x8 __attribute__((ext_vector_type(8)));

#define AP 136   // a_lds row stride (bf16 elems): 64x136x2 = 17408 B
#define EP 132   // e_lds row stride (f32 elems):  64x132x4 = 33792 B

__device__ __forceinline__ short f2bf(float f) {
    union { float f; uint32_t u; } v; v.f = f;
    uint32_t r = v.u + 0x7FFFu + ((v.u >> 16) & 1u);   // round-to-nearest-even
    return (short)(r >> 16);
}
__device__ __forceinline__ float bf2f(short s) {
    union { uint32_t u; float f; } v; v.u = ((uint32_t)(uint16_t)s) << 16;
    return v.f;
}
// packed f32x2 -> bf16x2 (compiler emits packed cvt)
__device__ __forceinline__ int cvt2(float a, float b) {
    float2 t; t.x = a; t.y = b;
    __hip_bfloat162 h = __float22bfloat162_rn(t);
    int r; __builtin_memcpy(&r, &h, 4);
    return r;
}

// ---------------- K1: weight conversion ----------------
// Wall row layout: [0:128)=Wq, [128:256)=Wk, [256:384)=Wv, [384:512)=We (bias same order)
__global__ __launch_bounds__(256) void convert_weights(
        const float* __restrict__ Wq, const float* __restrict__ bq,
        const float* __restrict__ Wk, const float* __restrict__ bk,
        const float* __restrict__ We, const float* __restrict__ be,
        const float* __restrict__ Wv, const float* __restrict__ bv,
        short* __restrict__ Whi, short* __restrict__ Wlo, float* __restrict__ ball) {
    int idx = blockIdx.x * 256 + threadIdx.x;     // 0..65535 exact
    int wrow = idx >> 7;                          // 0..511
    int k = idx & 127;
    int which = wrow >> 7;                        // 0 Q, 1 K, 2 V, 3 E
    int r = wrow & 127;
    const float* Wsrc = which == 0 ? Wq : which == 1 ? Wk : which == 2 ? Wv : We;
    float f = Wsrc[r * 128 + k];
    short hi = f2bf(f);
    short lo = f2bf(f - bf2f(hi));
    Whi[idx] = hi; Wlo[idx] = lo;
    if (idx < 512) {
        int wh = idx >> 7; int rr = idx & 127;
        const float* bsrc = wh == 0 ? bq : wh == 1 ? bk : wh == 2 ? bv : be;
        ball[idx] = bsrc[rr];
    }
}

// ---------------- K2: fused QKV projection ----------------
// block = 256 threads = 4 waves; tile = 64 nodes x 128 cols, K=128.
// Stage x -> bf16 LDS once, hoist A-frags to regs, loop over {Q,K,V} weights.
__global__ __launch_bounds__(256) void qkv_kernel(
        const float* __restrict__ x,
        const short* __restrict__ Whi, const short* __restrict__ Wlo,
        const float* __restrict__ ball,
        float* __restrict__ Qb, float* __restrict__ Kb, float* __restrict__ Vb,
        int N) {
    __shared__ char lds[64 * AP * 2];
    const int t = threadIdx.x;
    const int m0 = blockIdx.x * 64;

    // stage x tile -> bf16 LDS
#pragma unroll
    for (int i = 0; i < 4; ++i) {
        int g = t + i * 256;                      // 8-float group id, 0..1023
        int row = g >> 4, c8 = g & 15;
        int grow = m0 + row;
        float4 f0 = {0.f,0.f,0.f,0.f}, f1 = {0.f,0.f,0.f,0.f};
        if (grow < N) {
            const float4* p = (const float4*)(x + (size_t)grow * 128 + c8 * 8);
            f0 = p[0]; f1 = p[1];
        }
        int4 v;
        v.x = cvt2(f0.x, f0.y); v.y = cvt2(f0.z, f0.w);
        v.z = cvt2(f1.x, f1.y); v.w = cvt2(f1.z, f1.w);
        *(int4*)(lds + row * (AP * 2) + c8 * 16) = v;
    }
    __syncthreads();

    const int w = t >> 6, lane = t & 63;
    const int r16 = lane & 15, g16 = lane >> 4;
    const int cb = w * 32;

    // hoist A fragments (shared across Q/K/V)
    bf16x8 a[4][4];
#pragma unroll
    for (int ks = 0; ks < 4; ++ks)
#pragma unroll
        for (int m = 0; m < 4; ++m)
            a[ks][m] = *(const bf16x8*)(lds + (m * 16 + r16) * (AP * 2) + ks * 64 + g16 * 16);

    for (int ct = 0; ct < 3; ++ct) {
        const int colbase = ct * 128;
        bf16x8 bh[2][4], bl[2][4];
#pragma unroll
        for (int n = 0; n < 2; ++n) {
            int colg = colbase + cb + n * 16 + r16;
#pragma unroll
            for (int ks = 0; ks < 4; ++ks) {
                bh[n][ks] = *(const bf16x8*)(Whi + colg * 128 + ks * 32 + g16 * 8);
                bl[n][ks] = *(const bf16x8*)(Wlo + colg * 128 + ks * 32 + g16 * 8);
            }
        }
        f32x4 acc[4][2];
#pragma unroll
        for (int m = 0; m < 4; ++m)
#pragma unroll
            for (int n = 0; n < 2; ++n) acc[m][n] = (f32x4){0.f,0.f,0.f,0.f};

#pragma unroll
        for (int ks = 0; ks < 4; ++ks)
#pragma unroll
            for (int m = 0; m < 4; ++m)
#pragma unroll
                for (int n = 0; n < 2; ++n) {
                    acc[m][n] = __builtin_amdgcn_mfma_f32_16x16x32_bf16(a[ks][m], bh[n][ks], acc[m][n], 0, 0, 0);
                    acc[m][n] = __builtin_amdgcn_mfma_f32_16x16x32_bf16(a[ks][m], bl[n][ks], acc[m][n], 0, 0, 0);
                }
        float bias[2];
#pragma unroll
        for (int n = 0; n < 2; ++n) bias[n] = ball[colbase + cb + n * 16 + r16];

        // direct fragment-layout store: C col = lane&15 (within 16), row = g16*4 + r
        float* outb = ct == 0 ? Qb : ct == 1 ? Kb : Vb;
#pragma unroll
        for (int m = 0; m < 4; ++m) {
            int grow = m0 + m * 16 + g16 * 4;
#pragma unroll
            for (int r = 0; r < 4; ++r) {
                if (grow + r < N) {
#pragma unroll
                    for (int n = 0; n < 2; ++n)
                        outb[(size_t)(grow + r) * 128 + cb + n * 16 + r16] = acc[m][n][r] + bias[n];
                }
            }
        }
    }
}

// ---------------- K3: edge kernel (E proj + score + histogram) ----------------
__global__ __launch_bounds__(256) void edge_kernel(
        const float* __restrict__ ea,
        const int* __restrict__ srcp, const int* __restrict__ dstp,
        const short* __restrict__ Whi, const short* __restrict__ Wlo,
        const float* __restrict__ ball,
        const float* __restrict__ Qb, const float* __restrict__ Kb,
        float* __restrict__ scores, int* __restrict__ counts, int NE) {
    __shared__ char lds[64 * EP * 4];
    const int t = threadIdx.x;
    const int e0 = blockIdx.x * 64;

#pragma unroll
    for (int i = 0; i < 4; ++i) {
        int g = t + i * 256;
        int row = g >> 4, c8 = g & 15;
        int grow = e0 + row;
        float4 f0 = {0.f,0.f,0.f,0.f}, f1 = {0.f,0.f,0.f,0.f};
        if (grow < NE) {
            const float4* p = (const float4*)(ea + (size_t)grow * 128 + c8 * 8);
            f0 = p[0]; f1 = p[1];
        }
        int4 v;
        v.x = cvt2(f0.x, f0.y); v.y = cvt2(f0.z, f0.w);
        v.z = cvt2(f1.x, f1.y); v.w = cvt2(f1.z, f1.w);
        *(int4*)(lds + row * (AP * 2) + c8 * 16) = v;
    }
    __syncthreads();

    const int w = t >> 6, lane = t & 63;
    const int r16 = lane & 15, g16 = lane >> 4;
    const int cb = w * 32;
    const int colbase = 384;                      // We rows in Wall

    bf16x8 bh[2][4], bl[2][4];
#pragma unroll
    for (int n = 0; n < 2; ++n) {
        int colg = colbase + cb + n * 16 + r16;
#pragma unroll
        for (int ks = 0; ks < 4; ++ks) {
            bh[n][ks] = *(const bf16x8*)(Whi + colg * 128 + ks * 32 + g16 * 8);
            bl[n][ks] = *(const bf16x8*)(Wlo + colg * 128 + ks * 32 + g16 * 8);
        }
    }
    f32x4 acc[4][2];
#pragma unroll
    for (int m = 0; m < 4; ++m)
#pragma unroll
        for (int n = 0; n < 2; ++n) acc[m][n] = (f32x4){0.f,0.f,0.f,0.f};

#pragma unroll
    for (int ks = 0; ks < 4; ++ks) {
        bf16x8 a[4];
#pragma unroll
        for (int m = 0; m < 4; ++m)
            a[m] = *(const bf16x8*)(lds + (m * 16 + r16) * (AP * 2) + ks * 64 + g16 * 16);
#pragma unroll
        for (int m = 0; m < 4; ++m)
#pragma unroll
            for (int n = 0; n < 2; ++n) {
                acc[m][n] = __builtin_amdgcn_mfma_f32_16x16x32_bf16(a[m], bh[n][ks], acc[m][n], 0, 0, 0);
                acc[m][n] = __builtin_amdgcn_mfma_f32_16x16x32_bf16(a[m], bl[n][ks], acc[m][n], 0, 0, 0);
            }
    }
    float bias[2];
#pragma unroll
    for (int n = 0; n < 2; ++n) bias[n] = ball[colbase + cb + n * 16 + r16];

    __syncthreads();
    float* e_lds = (float*)lds;
#pragma unroll
    for (int m = 0; m < 4; ++m)
#pragma unroll
        for (int n = 0; n < 2; ++n)
#pragma unroll
            for (int r = 0; r < 4; ++r) {
                int row = m * 16 + g16 * 4 + r;
                int col = cb + n * 16 + r16;
                e_lds[row * EP + col] = acc[m][n][r] + bias[n];
            }
    __syncthreads();

    // epilogue: per (edge, head) dot with K[src]*Q[dst]*scale, clamp, exp.
    // h==0 task also bumps the dst histogram (replaces hist_kernel).
#pragma unroll
    for (int it = 0; it < 2; ++it) {
        int task = t + it * 256;                  // 0..511
        int el = task >> 3, h = task & 7;
        int eg = e0 + el;
        if (eg < NE) {
            int s = srcp[eg], d = dstp[eg];
            if (h == 0) atomicAdd(&counts[d], 1);
            const float4* Kp = (const float4*)(Kb + (size_t)s * 128 + h * 16);
            const float4* Qp = (const float4*)(Qb + (size_t)d * 128 + h * 16);
            float dot = 0.f;
#pragma unroll
            for (int j = 0; j < 4; ++j) {
                float4 ev = *(const float4*)(lds + el * (EP * 4) + h * 64 + j * 16);
                float4 kv = Kp[j];
                float4 qv = Qp[j];
                dot += ev.x * kv.x * qv.x + ev.y * kv.y * qv.y
                     + ev.z * kv.z * qv.z + ev.w * kv.w * qv.w;
            }
            float sv = fminf(fmaxf(dot * 0.25f, -5.0f), 5.0f);
            scores[(size_t)eg * 8 + h] = __expf(sv);
        }
    }
}

// ---------------- K4: CSR build ----------------
__global__ __launch_bounds__(1024) void scan1_kernel(const int* __restrict__ counts,
                                                     int* __restrict__ incl,
                                                     int* __restrict__ partials, int n) {
    __shared__ int sh[1024];
    int t = threadIdx.x;
    int i = blockIdx.x * 1024 + t;
    sh[t] = (i < n) ? counts[i] : 0;
    for (int off = 1; off < 1024; off <<= 1) {
        __syncthreads();
        int xv = (t >= off) ? sh[t - off] : 0;
        __syncthreads();
        sh[t] += xv;
    }
    __syncthreads();
    if (i < n) incl[i] = sh[t];
    if (t == 1023) partials[blockIdx.x] = sh[1023];
}

__global__ __launch_bounds__(64) void scan2_kernel(int* __restrict__ partials, int nb) {
    __shared__ int sh[64];
    int t = threadIdx.x;
    sh[t] = (t < nb) ? partials[t] : 0;
    __syncthreads();
    if (t == 0) {
        int acc = 0;
        for (int b = 0; b < nb; ++b) { int v = sh[b]; sh[b] = acc; acc += v; }
    }
    __syncthreads();
    if (t < nb) partials[t] = sh[t];
}

__global__ __launch_bounds__(1024) void scan3_kernel(const int* __restrict__ counts,
                                                     int* __restrict__ offsets,
                                                     int* __restrict__ cursors,
                                                     const int* __restrict__ partials,
                                                     int n, int total) {
    int i = blockIdx.x * 1024 + threadIdx.x;
    if (i < n) {
        int off = offsets[i] - counts[i] + partials[blockIdx.x];
        offsets[i] = off;
        cursors[i] = off;
    } else if (i == n) {
        offsets[n] = total;
    }
}

__global__ __launch_bounds__(256) void scatter_kernel(const int* __restrict__ srcp,
                                                      const int* __restrict__ dstp,
                                                      int* __restrict__ cursors,
                                                      int2* __restrict__ ebuf, int NE) {
    int i = blockIdx.x * 256 + threadIdx.x;
    if (i < NE) {
        int d = dstp[i];
        int s = srcp[i];
        int pos = atomicAdd(&cursors[d], 1);
        int2 v; v.x = s * 128; v.y = i * 8;       // precomputed offsets into Vb / scores
        ebuf[pos] = v;
    }
}

// ---------------- K5: gather/aggregate ----------------
__global__ __launch_bounds__(256) void gather_kernel(
        const int* __restrict__ offsets, const int2* __restrict__ eb,
        const float* __restrict__ scores, const float* __restrict__ Vb,
        float* __restrict__ out, int N) {
    int node = blockIdx.x * 2 + (threadIdx.x >> 7);
    int col = threadIdx.x & 127;
    if (node >= N) return;
    int h = col >> 4;
    int beg = offsets[node], end = offsets[node + 1];
    float a0 = 0.f, a1 = 0.f, a2 = 0.f, a3 = 0.f;
    int j = beg;
    for (; j + 4 <= end; j += 4) {
        int2 e0 = eb[j], e1 = eb[j + 1], e2 = eb[j + 2], e3 = eb[j + 3];
        a0 += scores[e0.y + h] * Vb[e0.x + col];
        a1 += scores[e1.y + h] * Vb[e1.x + col];
        a2 += scores[e2.y + h] * Vb[e2.x + col];
        a3 += scores[e3.y + h] * Vb[e3.x + col];
    }
    for (; j < end; ++j) {
        int2 e = eb[j];
        a0 += scores[e.y + h] * Vb[e.x + col];
    }
    out[(size_t)node * 128 + col] = (a0 + a1) + (a2 + a3);
}

// ---------------- launcher ----------------
extern "C" void kernel_launch(void* const* d_in, const int* in_sizes, int n_in,
                              void* d_out, int out_size, void* d_ws, size_t ws_size,
                              hipStream_t stream) {
    const float* x   = (const float*)d_in[0];
    const float* ea  = (const float*)d_in[1];
    const int* eidx  = (const int*)d_in[2];
    const float* Wq  = (const float*)d_in[4];  const float* bq = (const float*)d_in[5];
    const float* Wk  = (const float*)d_in[6];  const float* bk = (const float*)d_in[7];
    const float* We  = (const float*)d_in[8];  const float* be = (const float*)d_in[9];
    const float* Wv  = (const float*)d_in[10]; const float* bv = (const float*)d_in[11];
    const int N  = in_sizes[0] / 128;
    const int NE = in_sizes[2] / 2;
    const int* srcp = eidx;
    const int* dstp = eidx + NE;
    float* out = (float*)d_out;

    char* ws = (char*)d_ws;
    size_t o = 0;
    auto alloc = [&](size_t b) { size_t r = o; o += (b + 255) & ~(size_t)255; return r; };
    float* Qb      = (float*)(ws + alloc((size_t)N * 128 * 4));
    float* Kb      = (float*)(ws + alloc((size_t)N * 128 * 4));
    float* Vb      = (float*)(ws + alloc((size_t)N * 128 * 4));
    float* scores  = (float*)(ws + alloc((size_t)NE * 8 * 4));
    short* Whi     = (short*)(ws + alloc(512 * 128 * 2));
    short* Wlo     = (short*)(ws + alloc(512 * 128 * 2));
    float* ball    = (float*)(ws + alloc(512 * 4));
    int* counts    = (int*)(ws + alloc((size_t)(N + 1) * 4));
    int* offsets   = (int*)(ws + alloc((size_t)(N + 1) * 4));
    int* cursors   = (int*)(ws + alloc((size_t)N * 4));
    int2* ebuf     = (int2*)(ws + alloc((size_t)NE * 8));
    int* partials  = (int*)(ws + alloc(64 * 4));
    (void)ws_size; (void)n_in; (void)out_size;

    (void)hipMemsetAsync(counts, 0, (size_t)(N + 1) * 4, stream);

    convert_weights<<<256, 256, 0, stream>>>(Wq, bq, Wk, bk, We, be, Wv, bv, Whi, Wlo, ball);

    qkv_kernel<<<(N + 63) / 64, 256, 0, stream>>>(x, Whi, Wlo, ball, Qb, Kb, Vb, N);

    edge_kernel<<<(NE + 63) / 64, 256, 0, stream>>>(ea, srcp, dstp, Whi, Wlo, ball,
                                                    Qb, Kb, scores, counts, NE);

    int nb = (N + 1023) / 1024;
    scan1_kernel<<<nb, 1024, 0, stream>>>(counts, offsets, partials, N);
    scan2_kernel<<<1, 64, 0, stream>>>(partials, nb);
    scan3_kernel<<<nb, 1024, 0, stream>>>(counts, offsets, cursors, partials, N, NE);
    scatter_kernel<<<(NE + 255) / 256, 256, 0, stream>>>(srcp, dstp, cursors, ebuf, NE);

    gather_kernel<<<(N + 1) / 2, 256, 0, stream>>>(offsets, ebuf, scores, Vb, out, N);
}